// Round 4
// baseline (5540.097 us; speedup 1.0000x reference)
//
#include <hip/hip_runtime.h>
#include <hip/hip_bf16.h>
#include <stdint.h>

// Problem constants
#define HD    256      // hidden
#define LL    50       // friend seq len
#define SS    50       // common seq len
#define NB    64       // batch
#define MAXF  32
#define NSEQ  2048     // NB*MAXF
#define MB    32       // sequences per block-pair (one 32-row MFMA M-tile)
#define NPAIR 64       // sequence groups
#define XP    264      // padded LDS row (bf16 elems): 528B rows, 16B aligned

typedef __attribute__((ext_vector_type(8)))  short bf16x8;
typedef __attribute__((ext_vector_type(16))) float f32x16;
typedef __attribute__((ext_vector_type(4)))  unsigned short u16x4;

__device__ __forceinline__ f32x16 mfma32(bf16x8 a, bf16x8 b, f32x16 c) {
    return __builtin_amdgcn_mfma_f32_32x32x16_bf16(a, b, c, 0, 0, 0);
}

__device__ __forceinline__ unsigned short f2bf_rne(float f) {
    union { float f; uint32_t u; } v; v.f = f;
    uint32_t u = v.u;
    uint32_t r = u + 0x7FFFu + ((u >> 16) & 1u);
    return (unsigned short)(r >> 16);
}
__device__ __forceinline__ float bf2f(unsigned short b) {
    union { float f; uint32_t u; } v; v.u = ((uint32_t)b) << 16;
    return v.f;
}

// ---------------------------------------------------------------------------
// Pack weights -> per-wave MFMA 32x32x16 fragment stream + Wf^T.
// 8-slice layout: wpk index = ((((cw*2+l)*2 + m)*16 + ks)*6 + fr)*512 + lane*8 + j
//   fr = gate*2 + plane  (gate r/z/n, plane hi/lo)
//   W row n = gate*256 + cw*32 + (lane&31)    (col-wave cw owns cols [32cw,32cw+32))
//   k       = ks*16 + (lane>>5)*8 + j
// ---------------------------------------------------------------------------
__global__ void pack_kernel(const float* __restrict__ Wih0, const float* __restrict__ Whh0,
                            const float* __restrict__ Wih1, const float* __restrict__ Whh1,
                            const float* __restrict__ Wf,
                            unsigned short* __restrict__ wpk,
                            float* __restrict__ WfT) {
    int idx = blockIdx.x * blockDim.x + threadIdx.x;
    const int TOTW = 1572864;
    if (idx < TOTW) {
        int j    = idx & 7;
        int lane = (idx >> 3) & 63;
        int fr   = (idx >> 9) % 6;
        int t2   = (idx >> 9) / 6;           // ((cw*2+l)*2+m)*16+ks
        int ks   = t2 & 15;
        int m    = (t2 >> 4) & 1;
        int l    = (t2 >> 5) & 1;
        int cww  = t2 >> 6;                  // 0..7
        int gate = fr >> 1, plane = fr & 1;
        const float* W = (l == 0) ? (m == 0 ? Wih0 : Whh0)
                                  : (m == 0 ? Wih1 : Whh1);
        int n = gate * 256 + cww * 32 + (lane & 31);
        int k = ks * 16 + (lane >> 5) * 8 + j;
        float v = W[n * HD + k];
        unsigned short hi = f2bf_rne(v);
        wpk[idx] = plane ? f2bf_rne(v - bf2f(hi)) : hi;
    } else {
        int idx2 = idx - TOTW;
        if (idx2 < 512 * 256) {              // WfT[k][h] = Wf[h][k]
            int k = idx2 >> 8; int h = idx2 & 255;
            WfT[k * 256 + h] = Wf[h * 512 + k];
        }
    }
}

// ---------------------------------------------------------------------------
// Counting sort of the 2048 sequences by friend_len (1..50), ascending.
// Also clears the 256 pair-exchange flags (must be zero each launch).
// ---------------------------------------------------------------------------
__global__ void sort_kernel(const int* __restrict__ flen, int* __restrict__ sid,
                            int* __restrict__ xflag) {
    __shared__ int hist[64];
    __shared__ int offs[64];
    int tid = threadIdx.x;
    xflag[tid] = 0;                       // 256 flags, blockDim = 256
    if (tid < 64) hist[tid] = 0;
    __syncthreads();
    for (int i = tid; i < NSEQ; i += blockDim.x) atomicAdd(&hist[flen[i]], 1);
    __syncthreads();
    if (tid == 0) {
        int acc = 0;
        for (int v = 1; v <= 50; v++) { offs[v] = acc; acc += hist[v]; }
    }
    __syncthreads();
    for (int i = tid; i < NSEQ; i += blockDim.x) {
        int pos = atomicAdd(&offs[flen[i]], 1);
        sid[pos] = i;
    }
}

// ---------------------------------------------------------------------------
// Fused 2-layer GRU, N-SPLIT ACROSS CU PAIRS.
// Rounds 0-3 established the kernel is bound by per-CU L2->L1 fill of the
// weight stream (~30 B/cy): 3 MB/step/CU -> ~44 us/step regardless of
// waves/SIMD. This version splits the 256 output columns across two blocks
// (blockIdx b: pair g = b&63, half = b>>6; partners b and b+64 land on the
// SAME XCD since 64%8==0). Each block streams HALF the weights (1.5 MB/step)
// and exchanges its 32x128 hi/lo hidden half (16 KB) per layer through L2,
// with parity-double-buffered data + monotonic release/acquire flags.
// 128 blocks x 256 thr (4 waves), 1 block/CU (LDS), 1 wave/SIMD -> 512-VGPR
// budget, spill-free 4-buffer weight rotation. Arithmetic bit-identical to
// round-3 (exchange carries exact hi/lo planes).
// ---------------------------------------------------------------------------
__global__ __launch_bounds__(256) __attribute__((amdgpu_waves_per_eu(1, 1)))
void gru_kernel(const float* __restrict__ friend_x,
                const int* __restrict__ flen,
                const int* __restrict__ sid,
                const unsigned short* __restrict__ wpk,
                const float* __restrict__ bih0, const float* __restrict__ bhh0,
                const float* __restrict__ bih1, const float* __restrict__ bhh1,
                float* __restrict__ friend_last,
                uint32_t* __restrict__ xbuf, int* __restrict__ xflag) {
    __shared__ __align__(16) unsigned short Xhi[MB][XP],  Xlo[MB][XP];
    __shared__ __align__(16) unsigned short H0hi[MB][XP], H0lo[MB][XP];
    __shared__ __align__(16) unsigned short H1hi[MB][XP], H1lo[MB][XP];
    __shared__ int sidS[MB], lenS[MB];

    const int tid  = threadIdx.x;
    const int g    = blockIdx.x & 63;   // sequence group
    const int hb   = blockIdx.x >> 6;   // 0: cols 0..127, 1: cols 128..255
    const int oth  = hb ^ 1;
    const int wv   = tid >> 6;          // 0..3
    const int lane = tid & 63;
    const int l31  = lane & 31;
    const int half = lane >> 5;
    const int cw   = hb * 4 + wv;       // column-wave 0..7 (wpk slice)

    if (tid < MB) {
        int s_ = sid[g * MB + tid];
        sidS[tid] = s_;
        lenS[tid] = flen[s_];
    }
    for (int i = tid; i < MB * XP / 2; i += 256) {
        ((uint32_t*)&H0hi[0][0])[i] = 0; ((uint32_t*)&H0lo[0][0])[i] = 0;
        ((uint32_t*)&H1hi[0][0])[i] = 0; ((uint32_t*)&H1lo[0][0])[i] = 0;
    }
    __syncthreads();

    int maxlen = 0;
#pragma unroll
    for (int s = 0; s < MB; s++) maxlen = max(maxlen, lenS[s]);

    const int j0 = cw * 32 + l31;       // this lane's gate column

    // biases (acc-init values); n-gate input/hidden kept separate
    float b0R  = bih0[j0] + bhh0[j0];
    float b0Z  = bih0[256 + j0] + bhh0[256 + j0];
    float b0Ni = bih0[512 + j0];
    float b0Nh = bhh0[512 + j0];
    float b1R  = bih1[j0] + bhh1[j0];
    float b1Z  = bih1[256 + j0] + bhh1[256 + j0];
    float b1Ni = bih1[512 + j0];
    float b1Nh = bhh1[512 + j0];

    int srow[8];                        // staged sequence ids (rows wv*8..wv*8+7)
#pragma unroll
    for (int r = 0; r < 8; r++) srow[r] = sidS[wv * 8 + r];

    const int fragBase = l31 * XP + half * 8;

    auto loadB6 = [&](bf16x8* B, const unsigned short* p) {
#pragma unroll
        for (int f = 0; f < 6; f++) B[f] = *(const bf16x8*)(p + f * 512);
    };

    // 9 MFMAs: one K=16 step for this wave's 32-col subtile of all 3 gates.
    auto compute9 = [&](const bf16x8* B, bf16x8 ah, bf16x8 al,
                        f32x16& aRs, f32x16& aZs, f32x16& aNs) {
        aRs = mfma32(ah, B[0], aRs);
        aZs = mfma32(ah, B[2], aZs);
        aNs = mfma32(ah, B[4], aNs);
        aRs = mfma32(al, B[0], aRs);
        aZs = mfma32(al, B[2], aZs);
        aNs = mfma32(al, B[4], aNs);
        aRs = mfma32(ah, B[1], aRs);
        aZs = mfma32(ah, B[3], aZs);
        aNs = mfma32(ah, B[5], aNs);
    };

    // one m-phase (16 K-steps): 4-buffer rotation, lookahead 3 batches.
    auto halfMM = [&](const unsigned short* pm,
                      const unsigned short* Ah_, const unsigned short* Al_,
                      f32x16& aRs, f32x16& aZs, f32x16& aNs) {
        bf16x8 B0[6], B1[6], B2[6], B3[6];
        loadB6(B0, pm);
        loadB6(B1, pm + 3072);
        loadB6(B2, pm + 6144);
        loadB6(B3, pm + 9216);
        bf16x8 ahA = *(const bf16x8*)(Ah_ + fragBase);
        bf16x8 alA = *(const bf16x8*)(Al_ + fragBase);
        bf16x8 ahB, alB;
#pragma unroll
        for (int base = 0; base < 16; base += 4) {
            ahB = *(const bf16x8*)(Ah_ + fragBase + (base + 1) * 16);
            alB = *(const bf16x8*)(Al_ + fragBase + (base + 1) * 16);
            compute9(B0, ahA, alA, aRs, aZs, aNs);
            if (base + 4 < 16) loadB6(B0, pm + (size_t)(base + 4) * 3072);
            ahA = *(const bf16x8*)(Ah_ + fragBase + (base + 2) * 16);
            alA = *(const bf16x8*)(Al_ + fragBase + (base + 2) * 16);
            compute9(B1, ahB, alB, aRs, aZs, aNs);
            if (base + 5 < 16) loadB6(B1, pm + (size_t)(base + 5) * 3072);
            ahB = *(const bf16x8*)(Ah_ + fragBase + (base + 3) * 16);
            alB = *(const bf16x8*)(Al_ + fragBase + (base + 3) * 16);
            compute9(B2, ahA, alA, aRs, aZs, aNs);
            if (base + 6 < 16) loadB6(B2, pm + (size_t)(base + 6) * 3072);
            {
                const int kn = (base + 4 < 16) ? base + 4 : 15;  // clamped prefetch
                ahA = *(const bf16x8*)(Ah_ + fragBase + kn * 16);
                alA = *(const bf16x8*)(Al_ + fragBase + kn * 16);
            }
            compute9(B3, ahB, alB, aRs, aZs, aNs);
            if (base + 7 < 16) loadB6(B3, pm + (size_t)(base + 7) * 3072);
        }
    };

    auto initAcc = [&](f32x16& a, float b) {
        f32x16 v;
#pragma unroll
        for (int i = 0; i < 16; i++) v[i] = b;
        a = v;
    };

    // gate epilogue; C-layout: col = lane&31, row = (reg&3)+8*(reg>>2)+4*half.
    // Writes own-col LDS planes + 32x128 u32 (hi|lo<<16) exchange block.
    auto epi = [&](f32x16& aRs, f32x16& aZs, f32x16& aNis, f32x16& aNhs,
                   unsigned short (*Ohi)[XP], unsigned short (*Olo)[XP],
                   uint32_t* xb, bool gather, int t) {
        const int j = j0;
        const int c = wv * 32 + l31;    // col within this block's half
#pragma unroll
        for (int rg = 0; rg < 16; rg++) {
            const int row = (rg & 3) + ((rg >> 2) << 3) + (half << 2);
            float hOld = bf2f(Ohi[row][j]) + bf2f(Olo[row][j]);
            float rr = 1.f / (1.f + __expf(-aRs[rg]));
            float zz = 1.f / (1.f + __expf(-aZs[rg]));
            float nx = aNis[rg] + rr * aNhs[rg];
            float e  = __expf(-2.f * fabsf(nx));
            float th = 1.f - 2.f * e / (1.f + e);
            th = (nx < 0.f) ? -th : th;
            float hNew = (1.f - zz) * th + zz * hOld;
            unsigned short hi_ = f2bf_rne(hNew);
            unsigned short lo_ = f2bf_rne(hNew - bf2f(hi_));
            Ohi[row][j] = hi_;
            Olo[row][j] = lo_;
            xb[row * 128 + c] = (uint32_t)hi_ | ((uint32_t)lo_ << 16);
            if (gather && t == lenS[row] - 1)
                friend_last[(size_t)sidS[row] * HD + j] = hNew;
        }
    };

    // pull partner's 32x128 half into the LDS planes
    auto pullPartner = [&](const uint32_t* xr,
                           unsigned short (*Ohi)[XP], unsigned short (*Olo)[XP]) {
        for (int i = tid; i < 4096; i += 256) {
            uint32_t v = xr[i];
            int row = i >> 7, c = i & 127;
            int col = oth * 128 + c;
            Ohi[row][col] = (unsigned short)(v & 0xffffu);
            Olo[row][col] = (unsigned short)(v >> 16);
        }
    };

    auto stageWrite = [&](const float4* sx) {
#pragma unroll
        for (int r = 0; r < 8; r++) {
            int row = wv * 8 + r;
            float vals[4] = { sx[r].x, sx[r].y, sx[r].z, sx[r].w };
            u16x4 hi4, lo4;
#pragma unroll
            for (int e2 = 0; e2 < 4; e2++) {
                unsigned short h_ = f2bf_rne(vals[e2]);
                hi4[e2] = h_;
                lo4[e2] = f2bf_rne(vals[e2] - bf2f(h_));
            }
            *(u16x4*)&Xhi[row][lane * 4] = hi4;
            *(u16x4*)&Xlo[row][lane * 4] = lo4;
        }
    };

    // stage x(0)
    {
        float4 sx[8];
#pragma unroll
        for (int r = 0; r < 8; r++)
            sx[r] = ((const float4*)(friend_x + ((size_t)srow[r] * LL) * HD))[lane];
        stageWrite(sx);
    }
    __syncthreads();

    // per-col-wave weight bases: (cw*2+l)*98304 ; +49152 for the m-phase
    const unsigned short* pw0 = wpk + (size_t)(cw * 2 + 0) * 98304 + (size_t)lane * 8;
    const unsigned short* pw1 = wpk + (size_t)(cw * 2 + 1) * 98304 + (size_t)lane * 8;

    int* fl0o = &xflag[(g * 2 + 0) * 2 + hb];
    int* fl0p = &xflag[(g * 2 + 0) * 2 + oth];
    int* fl1o = &xflag[(g * 2 + 1) * 2 + hb];
    int* fl1p = &xflag[(g * 2 + 1) * 2 + oth];

#pragma unroll 1
    for (int t = 0; t < maxlen; t++) {
        int par = t & 1;
        uint32_t* xb0 = xbuf + ((((size_t)par * NPAIR + g) * 2 + 0) * 2 + hb) * 4096;
        uint32_t* xb1 = xbuf + ((((size_t)par * NPAIR + g) * 2 + 1) * 2 + hb) * 4096;
        const uint32_t* xr0 = xbuf + ((((size_t)par * NPAIR + g) * 2 + 0) * 2 + oth) * 4096;
        const uint32_t* xr1 = xbuf + ((((size_t)par * NPAIR + g) * 2 + 1) * 2 + oth) * 4096;

        // issue next-step staging loads early (held in regs through layer 0)
        int tn = (t + 1 < maxlen) ? t + 1 : t;
        float4 sx[8];
#pragma unroll
        for (int r = 0; r < 8; r++)
            sx[r] = ((const float4*)(friend_x + ((size_t)srow[r] * LL + tn) * HD))[lane];

        // ---- Layer 0: gates = x(t)·Wih0 + h0·Whh0 (own 128 cols, full K) ----
        f32x16 aR, aZ, aNi, aNh;
        initAcc(aR, b0R); initAcc(aZ, b0Z); initAcc(aNi, b0Ni); initAcc(aNh, b0Nh);
        halfMM(pw0,         &Xhi[0][0],  &Xlo[0][0],  aR, aZ, aNi);
        halfMM(pw0 + 49152, &H0hi[0][0], &H0lo[0][0], aR, aZ, aNh);
        __syncthreads();                       // B1: X/H0 plane reads complete
        epi(aR, aZ, aNi, aNh, H0hi, H0lo, xb0, false, t);
        stageWrite(sx);                        // overwrite X plane with x(t+1)
        __threadfence();
        __syncthreads();                       // B2: all h0 stores fenced
        if (tid == 0)
            __hip_atomic_store(fl0o, t + 1, __ATOMIC_RELEASE, __HIP_MEMORY_SCOPE_AGENT);
        while (__hip_atomic_load(fl0p, __ATOMIC_ACQUIRE, __HIP_MEMORY_SCOPE_AGENT) < t + 1)
            __builtin_amdgcn_s_sleep(2);
        pullPartner(xr0, H0hi, H0lo);
        __syncthreads();                       // B3: H0 planes complete (both halves)

        // ---- Layer 1: gates = h0(t)·Wih1 + h1·Whh1 ----
        initAcc(aR, b1R); initAcc(aZ, b1Z); initAcc(aNi, b1Ni); initAcc(aNh, b1Nh);
        halfMM(pw1,         &H0hi[0][0], &H0lo[0][0], aR, aZ, aNi);
        halfMM(pw1 + 49152, &H1hi[0][0], &H1lo[0][0], aR, aZ, aNh);
        __syncthreads();                       // B4: H0/H1 plane reads complete
        epi(aR, aZ, aNi, aNh, H1hi, H1lo, xb1, true, t);
        __threadfence();
        __syncthreads();                       // B5: all h1 stores fenced
        if (tid == 0)
            __hip_atomic_store(fl1o, t + 1, __ATOMIC_RELEASE, __HIP_MEMORY_SCOPE_AGENT);
        while (__hip_atomic_load(fl1p, __ATOMIC_ACQUIRE, __HIP_MEMORY_SCOPE_AGENT) < t + 1)
            __builtin_amdgcn_s_sleep(2);
        pullPartner(xr1, H1hi, H1lo);
        __syncthreads();                       // B6: H1 planes complete for t+1
    }
}

// ---------------------------------------------------------------------------
// Fused: sf[n,h] = Wf[h,:256]·self_x[b] + Wf[h,256:]·fl[n]; v[n,h] = Wb[:,h]·sf[n,:]
// ---------------------------------------------------------------------------
__global__ __launch_bounds__(256)
void sfv_kernel(const float* __restrict__ self_x, const float* __restrict__ fl,
                const float* __restrict__ WfT, const float* __restrict__ Wb,
                float* __restrict__ vout) {
    __shared__ float S[256];
    __shared__ float T[256][33];   // phase1: fl^T [k][f]; phase2: sf^T [g][f]
    int b = blockIdx.x, tid = threadIdx.x;
    S[tid] = self_x[b * 256 + tid];
    for (int i = tid; i < 32 * 256; i += 256) {
        int f = i >> 8, k = i & 255;
        T[k][f] = fl[((size_t)(b * 32 + f)) * 256 + k];
    }
    __syncthreads();
    float acc0 = 0.f;
    for (int k = 0; k < 256; k++) acc0 += WfT[k * 256 + tid] * S[k];
    float acc[32];
#pragma unroll
    for (int f = 0; f < 32; f++) acc[f] = acc0;
    for (int k = 0; k < 256; k++) {
        float w = WfT[(256 + k) * 256 + tid];
#pragma unroll
        for (int f = 0; f < 32; f++) acc[f] += w * T[k][f];
    }
    __syncthreads();
#pragma unroll
    for (int f = 0; f < 32; f++) T[tid][f] = acc[f];   // sf^T into LDS
    __syncthreads();
    float av[32];
#pragma unroll
    for (int f = 0; f < 32; f++) av[f] = 0.f;
    for (int gg = 0; gg < 256; gg++) {
        float w = Wb[gg * 256 + tid];
#pragma unroll
        for (int f = 0; f < 32; f++) av[f] += w * T[gg][f];
    }
#pragma unroll
    for (int f = 0; f < 32; f++)
        vout[((size_t)(b * 32 + f)) * 256 + tid] = av[f];
}

// ---------------------------------------------------------------------------
// tf[n] = sum_s softplus(common_x[n,s,:]·v[n,:]) * exp(-time) * (s < clen)
// ---------------------------------------------------------------------------
__global__ __launch_bounds__(256)
void tf_kernel(const float* __restrict__ common_x, const float* __restrict__ common_time,
               const int* __restrict__ clen, const float* __restrict__ v,
               float* __restrict__ tf) {
    __shared__ float V[256];
    __shared__ float partial[4];
    int n = blockIdx.x, tid = threadIdx.x, wv = tid >> 6, lane = tid & 63;
    V[tid] = v[(size_t)n * 256 + tid];
    __syncthreads();
    float4 vv = ((const float4*)V)[lane];
    int cl = clen[n];
    float acc = 0.f;
    for (int s = wv; s < SS; s += 4) {
        float4 cx = ((const float4*)(common_x + ((size_t)n * SS + s) * HD))[lane];
        float d = cx.x * vv.x + cx.y * vv.y + cx.z * vv.z + cx.w * vv.w;
#pragma unroll
        for (int off = 32; off; off >>= 1) d += __shfl_xor(d, off);
        if (lane == 0 && s < cl) {
            float sp = (d > 20.f) ? d : log1pf(__expf(d));
            acc += sp * __expf(-common_time[n * SS + s]);
        }
    }
    if (lane == 0) partial[wv] = acc;
    __syncthreads();
    if (tid == 0) tf[n] = partial[0] + partial[1] + partial[2] + partial[3];
}

// ---------------------------------------------------------------------------
// softmax over padded MAXF (invalid logits exactly 0) + weighted sum.
// ---------------------------------------------------------------------------
__global__ __launch_bounds__(256)
void out_kernel(const float* __restrict__ tf, const int* __restrict__ fnum,
                const float* __restrict__ fl, float* __restrict__ out) {
    __shared__ float e[32];
    __shared__ float tfm[32];
    __shared__ float Zs;
    int b = blockIdx.x, tid = threadIdx.x;
    int nv = fnum[b];
    if (tid < 32) tfm[tid] = (tid < nv) ? tf[b * 32 + tid] : 0.f;
    __syncthreads();
    if (tid == 0) {
        float m = tfm[0];
        for (int f = 1; f < 32; f++) m = fmaxf(m, tfm[f]);
        float Z = 0.f;
        for (int f = 0; f < 32; f++) { e[f] = __expf(tfm[f] - m); Z += e[f]; }
        Zs = Z;
    }
    __syncthreads();
    float Zi = 1.f / Zs;
    float o = 0.f;
    for (int f = 0; f < nv; f++)
        o += e[f] * Zi * fl[((size_t)(b * 32 + f)) * 256 + tid];
    out[b * 256 + tid] = o;
}

// ---------------------------------------------------------------------------
extern "C" void kernel_launch(void* const* d_in, const int* in_sizes, int n_in,
                              void* d_out, int out_size, void* d_ws, size_t ws_size,
                              hipStream_t stream) {
    (void)in_sizes; (void)n_in; (void)out_size; (void)ws_size;
    const float* self_x      = (const float*)d_in[0];
    const float* common_x    = (const float*)d_in[1];
    const float* common_time = (const float*)d_in[2];
    const float* friend_x    = (const float*)d_in[3];
    const float* Wih0 = (const float*)d_in[4];
    const float* Whh0 = (const float*)d_in[5];
    const float* bih0 = (const float*)d_in[6];
    const float* bhh0 = (const float*)d_in[7];
    const float* Wih1 = (const float*)d_in[8];
    const float* Whh1 = (const float*)d_in[9];
    const float* bih1 = (const float*)d_in[10];
    const float* bhh1 = (const float*)d_in[11];
    const float* Wf   = (const float*)d_in[12];
    const float* Wb   = (const float*)d_in[13];
    const int* flen   = (const int*)d_in[14];
    const int* fnum   = (const int*)d_in[15];
    const int* clen   = (const int*)d_in[16];
    float* out = (float*)d_out;

    char* ws = (char*)d_ws;
    unsigned short* wpk = (unsigned short*)ws; ws += (size_t)1572864 * 2;
    float* WfT = (float*)ws;  ws += (size_t)512 * 256 * 4;
    int*   sid = (int*)ws;    ws += (size_t)2048 * 4;
    float* fl  = (float*)ws;  ws += (size_t)2048 * 256 * 4;
    float* vv  = (float*)ws;  ws += (size_t)2048 * 256 * 4;
    float* tf  = (float*)ws;  ws += (size_t)2048 * 4;
    uint32_t* xbuf = (uint32_t*)ws; ws += (size_t)2 * NPAIR * 2 * 2 * 4096 * 4; // 8 MB
    int* xflag = (int*)ws;    ws += (size_t)256 * 4;

    pack_kernel<<<6656, 256, 0, stream>>>(Wih0, Whh0, Wih1, Whh1, Wf, wpk, WfT);
    sort_kernel<<<1, 256, 0, stream>>>(flen, sid, xflag);
    gru_kernel<<<128, 256, 0, stream>>>(friend_x, flen, sid, wpk,
                                        bih0, bhh0, bih1, bhh1, fl, xbuf, xflag);
    sfv_kernel<<<64, 256, 0, stream>>>(self_x, fl, WfT, Wb, vv);
    tf_kernel<<<2048, 256, 0, stream>>>(common_x, common_time, clen, vv, tf);
    out_kernel<<<64, 256, 0, stream>>>(tf, fnum, fl, out);
}

// Round 6
// 4737.725 us; speedup vs baseline: 1.1694x; 1.1694x over previous
//
#include <hip/hip_runtime.h>
#include <hip/hip_bf16.h>
#include <stdint.h>

// Problem constants
#define HD    256      // hidden
#define LL    50       // friend seq len
#define SS    50       // common seq len
#define NB    64       // batch
#define MAXF  32
#define NSEQ  2048     // NB*MAXF
#define MB    32       // sequences per pair (one 32-row MFMA M-tile)
#define NPAIR 64       // sequence groups
#define XP    264      // padded LDS row (bf16 elems): 528B rows, 16B aligned

// ctrl layout (ints): [0..255] xflag, [256..271] xcdCtr, [272..399] pairState, [400] gCtr
#define C_XCD   256
#define C_PAIR  272
#define C_GCTR  400

typedef __attribute__((ext_vector_type(8)))  short bf16x8;
typedef __attribute__((ext_vector_type(16))) float f32x16;
typedef __attribute__((ext_vector_type(4)))  unsigned short u16x4;

__device__ __forceinline__ f32x16 mfma32(bf16x8 a, bf16x8 b, f32x16 c) {
    return __builtin_amdgcn_mfma_f32_32x32x16_bf16(a, b, c, 0, 0, 0);
}

__device__ __forceinline__ unsigned short f2bf_rne(float f) {
    union { float f; uint32_t u; } v; v.f = f;
    uint32_t u = v.u;
    uint32_t r = u + 0x7FFFu + ((u >> 16) & 1u);
    return (unsigned short)(r >> 16);
}
__device__ __forceinline__ float bf2f(unsigned short b) {
    union { float f; uint32_t u; } v; v.u = ((uint32_t)b) << 16;
    return v.f;
}

// ---------------------------------------------------------------------------
// Pack weights -> per-wave MFMA 32x32x16 fragment stream + Wf^T.
// 8-slice layout: wpk index = ((((cw*2+l)*2 + m)*16 + ks)*6 + fr)*512 + lane*8 + j
//   fr = gate*2 + plane  (gate r/z/n, plane hi/lo)
//   W row n = gate*256 + cw*32 + (lane&31)    (col-wave cw owns cols [32cw,32cw+32))
//   k       = ks*16 + (lane>>5)*8 + j
// ---------------------------------------------------------------------------
__global__ void pack_kernel(const float* __restrict__ Wih0, const float* __restrict__ Whh0,
                            const float* __restrict__ Wih1, const float* __restrict__ Whh1,
                            const float* __restrict__ Wf,
                            unsigned short* __restrict__ wpk,
                            float* __restrict__ WfT) {
    int idx = blockIdx.x * blockDim.x + threadIdx.x;
    const int TOTW = 1572864;
    if (idx < TOTW) {
        int j    = idx & 7;
        int lane = (idx >> 3) & 63;
        int fr   = (idx >> 9) % 6;
        int t2   = (idx >> 9) / 6;           // ((cw*2+l)*2+m)*16+ks
        int ks   = t2 & 15;
        int m    = (t2 >> 4) & 1;
        int l    = (t2 >> 5) & 1;
        int cww  = t2 >> 6;                  // 0..7
        int gate = fr >> 1, plane = fr & 1;
        const float* W = (l == 0) ? (m == 0 ? Wih0 : Whh0)
                                  : (m == 0 ? Wih1 : Whh1);
        int n = gate * 256 + cww * 32 + (lane & 31);
        int k = ks * 16 + (lane >> 5) * 8 + j;
        float v = W[n * HD + k];
        unsigned short hi = f2bf_rne(v);
        wpk[idx] = plane ? f2bf_rne(v - bf2f(hi)) : hi;
    } else {
        int idx2 = idx - TOTW;
        if (idx2 < 512 * 256) {              // WfT[k][h] = Wf[h][k]
            int k = idx2 >> 8; int h = idx2 & 255;
            WfT[k * 256 + h] = Wf[h * 512 + k];
        }
    }
}

// ---------------------------------------------------------------------------
// Counting sort of the 2048 sequences by friend_len (1..50), ascending.
// Also clears the 512-int control block (flags + pairing state).
// ---------------------------------------------------------------------------
__global__ void sort_kernel(const int* __restrict__ flen, int* __restrict__ sid,
                            int* __restrict__ ctrl) {
    __shared__ int hist[64];
    __shared__ int offs[64];
    int tid = threadIdx.x;
    ctrl[tid] = 0; ctrl[256 + tid] = 0;   // clear 512 ints
    if (tid < 64) hist[tid] = 0;
    __syncthreads();
    for (int i = tid; i < NSEQ; i += blockDim.x) atomicAdd(&hist[flen[i]], 1);
    __syncthreads();
    if (tid == 0) {
        int acc = 0;
        for (int v = 1; v <= 50; v++) { offs[v] = acc; acc += hist[v]; }
    }
    __syncthreads();
    for (int i = tid; i < NSEQ; i += blockDim.x) {
        int pos = atomicAdd(&offs[flen[i]], 1);
        sid[pos] = i;
    }
}

// ---------------------------------------------------------------------------
// Fused 2-layer GRU, N-SPLIT across SAME-XCD CU pairs.
// Rounds 4/5 lesson: cross-XCD sync needs L2 invalidates (round-4: FETCH
// 2.27 GB, 2.3x slow) or LLC-visibility tricks that hung (round-5). Fix:
// pairs are formed INSIDE an XCD via s_getreg(HW_REG_XCC_ID) + per-XCD slot
// counter, so the shared (coherent) XCD L2 is the exchange medium:
//   writer: atomic (sc0, write-through) data stores -> __syncthreads
//           (vmcnt(0) drain => data at L2) -> relaxed RMW flag exchange
//   reader: tid0 polls flag with relaxed RMW (fetch_add 0) -> barrier ->
//           relaxed atomic loads (sc0, L1-bypass) pull data from L2.
// NO cache-maintenance instructions anywhere. Pairing is hang-free: role-1's
// publish-wait is bounded by role-0 straight-line code; role-0's confirm-wait
// times out -> SOLO fallback (block computes both column halves, no
// exchange). Paired block streams HALF the weights (1.5 MB/step).
// 128 blocks x 256 thr, 1 block/CU (LDS), 1 wave/SIMD. Math bit-identical
// to rounds 3/4 (exact hi/lo exchange).
// ---------------------------------------------------------------------------
__global__ __launch_bounds__(256) __attribute__((amdgpu_waves_per_eu(1, 1)))
void gru_kernel(const float* __restrict__ friend_x,
                const int* __restrict__ flen,
                const int* __restrict__ sid,
                const unsigned short* __restrict__ wpk,
                const float* __restrict__ bih0, const float* __restrict__ bhh0,
                const float* __restrict__ bih1, const float* __restrict__ bhh1,
                float* __restrict__ friend_last,
                uint32_t* __restrict__ xbuf, int* __restrict__ ctrl) {
    __shared__ __align__(16) unsigned short Xhi[MB][XP],  Xlo[MB][XP];
    __shared__ __align__(16) unsigned short H0hi[MB][XP], H0lo[MB][XP];
    __shared__ __align__(16) unsigned short H1hi[MB][XP], H1lo[MB][XP];
    __shared__ int sidS[MB], lenS[MB];
    __shared__ int pairInfo[3];         // g, paired, role

    const int tid  = threadIdx.x;
    const int wv   = tid >> 6;          // 0..3
    const int lane = tid & 63;
    const int l31  = lane & 31;
    const int half = lane >> 5;

    // ---- same-XCD dynamic pairing (tid 0) ----
    if (tid == 0) {
        uint32_t xcd;
        asm volatile("s_getreg_b32 %0, hwreg(HW_REG_XCC_ID, 0, 32)" : "=s"(xcd));
        xcd &= 7u;
        int slot = __hip_atomic_fetch_add(&ctrl[C_XCD + xcd], 1,
                                          __ATOMIC_RELAXED, __HIP_MEMORY_SCOPE_AGENT);
        int role = slot & 1, pidx = slot >> 1;
        int* cell = &ctrl[C_PAIR + xcd * 16 + pidx];
        int g, paired;
        if (role == 0) {
            g = atomicAdd(&ctrl[C_GCTR], 1);
            __hip_atomic_exchange(cell, g + 1, __ATOMIC_RELAXED, __HIP_MEMORY_SCOPE_AGENT);
            paired = 0;
            for (int it = 0; it < 20000; ++it) {        // ~ms-scale timeout
                if (__hip_atomic_fetch_add(cell, 0, __ATOMIC_RELAXED,
                                           __HIP_MEMORY_SCOPE_AGENT) == -2) { paired = 1; break; }
                __builtin_amdgcn_s_sleep(8);
            }
            if (!paired) {
                int old = __hip_atomic_exchange(cell, -1, __ATOMIC_RELAXED,
                                                __HIP_MEMORY_SCOPE_AGENT);
                if (old == -2) paired = 1;              // partner confirmed during race
            }
        } else {
            int v;
            while ((v = __hip_atomic_fetch_add(cell, 0, __ATOMIC_RELAXED,
                                               __HIP_MEMORY_SCOPE_AGENT)) == 0)
                __builtin_amdgcn_s_sleep(2);            // bounded: role-0 publishes next
            if (v == -1) { paired = 0; g = atomicAdd(&ctrl[C_GCTR], 1); }
            else {
                int old = __hip_atomic_exchange(cell, -2, __ATOMIC_RELAXED,
                                                __HIP_MEMORY_SCOPE_AGENT);
                if (old == -1) { paired = 0; g = atomicAdd(&ctrl[C_GCTR], 1); }
                else           { paired = 1; g = old - 1; }
            }
        }
        pairInfo[0] = g; pairInfo[1] = paired; pairInfo[2] = role;
    }
    __syncthreads();
    const int g      = pairInfo[0];
    const int paired = pairInfo[1];
    const int role   = pairInfo[2];
    if (g >= NPAIR) return;             // over-claim under solo fallback: no work

    if (tid < MB) {
        int s_ = sid[g * MB + tid];
        sidS[tid] = s_;
        lenS[tid] = flen[s_];
    }
    for (int i = tid; i < MB * XP / 2; i += 256) {
        ((uint32_t*)&H0hi[0][0])[i] = 0; ((uint32_t*)&H0lo[0][0])[i] = 0;
        ((uint32_t*)&H1hi[0][0])[i] = 0; ((uint32_t*)&H1lo[0][0])[i] = 0;
    }
    __syncthreads();

    int maxlen = 0;
#pragma unroll
    for (int s = 0; s < MB; s++) maxlen = max(maxlen, lenS[s]);

    int srow[8];                        // staged sequence ids (rows wv*8..wv*8+7)
#pragma unroll
    for (int r = 0; r < 8; r++) srow[r] = sidS[wv * 8 + r];

    const int fragBase = l31 * XP + half * 8;

    auto loadB6 = [&](bf16x8* B, const unsigned short* p) {
#pragma unroll
        for (int f = 0; f < 6; f++) B[f] = *(const bf16x8*)(p + f * 512);
    };

    auto compute9 = [&](const bf16x8* B, bf16x8 ah, bf16x8 al,
                        f32x16& aRs, f32x16& aZs, f32x16& aNs) {
        aRs = mfma32(ah, B[0], aRs);
        aZs = mfma32(ah, B[2], aZs);
        aNs = mfma32(ah, B[4], aNs);
        aRs = mfma32(al, B[0], aRs);
        aZs = mfma32(al, B[2], aZs);
        aNs = mfma32(al, B[4], aNs);
        aRs = mfma32(ah, B[1], aRs);
        aZs = mfma32(ah, B[3], aZs);
        aNs = mfma32(ah, B[5], aNs);
    };

    // one m-phase (16 K-steps): 4-buffer rotation, lookahead 3 batches.
    auto halfMM = [&](const unsigned short* pm,
                      const unsigned short* Ah_, const unsigned short* Al_,
                      f32x16& aRs, f32x16& aZs, f32x16& aNs) {
        bf16x8 B0[6], B1[6], B2[6], B3[6];
        loadB6(B0, pm);
        loadB6(B1, pm + 3072);
        loadB6(B2, pm + 6144);
        loadB6(B3, pm + 9216);
        bf16x8 ahA = *(const bf16x8*)(Ah_ + fragBase);
        bf16x8 alA = *(const bf16x8*)(Al_ + fragBase);
        bf16x8 ahB, alB;
#pragma unroll
        for (int base = 0; base < 16; base += 4) {
            ahB = *(const bf16x8*)(Ah_ + fragBase + (base + 1) * 16);
            alB = *(const bf16x8*)(Al_ + fragBase + (base + 1) * 16);
            compute9(B0, ahA, alA, aRs, aZs, aNs);
            if (base + 4 < 16) loadB6(B0, pm + (size_t)(base + 4) * 3072);
            ahA = *(const bf16x8*)(Ah_ + fragBase + (base + 2) * 16);
            alA = *(const bf16x8*)(Al_ + fragBase + (base + 2) * 16);
            compute9(B1, ahB, alB, aRs, aZs, aNs);
            if (base + 5 < 16) loadB6(B1, pm + (size_t)(base + 5) * 3072);
            ahB = *(const bf16x8*)(Ah_ + fragBase + (base + 3) * 16);
            alB = *(const bf16x8*)(Al_ + fragBase + (base + 3) * 16);
            compute9(B2, ahA, alA, aRs, aZs, aNs);
            if (base + 6 < 16) loadB6(B2, pm + (size_t)(base + 6) * 3072);
            {
                const int kn = (base + 4 < 16) ? base + 4 : 15;  // clamped prefetch
                ahA = *(const bf16x8*)(Ah_ + fragBase + kn * 16);
                alA = *(const bf16x8*)(Al_ + fragBase + kn * 16);
            }
            compute9(B3, ahB, alB, aRs, aZs, aNs);
            if (base + 7 < 16) loadB6(B3, pm + (size_t)(base + 7) * 3072);
        }
    };

    auto initAcc = [&](f32x16& a, float b) {
        f32x16 v;
#pragma unroll
        for (int i = 0; i < 16; i++) v[i] = b;
        a = v;
    };

    // gate epilogue; C-layout: col = lane&31, row = (reg&3)+8*(reg>>2)+4*half.
    // hidden carry reconstructed as hi+lo from LDS planes. If xb != null,
    // also publish own 32x128 half as u32 (hi|lo<<16) via sc0 atomic stores.
    auto epi = [&](f32x16& aRs, f32x16& aZs, f32x16& aNis, f32x16& aNhs,
                   unsigned short (*Ohi)[XP], unsigned short (*Olo)[XP],
                   uint32_t* xb, int j, bool gather, int t) {
        const int c = wv * 32 + l31;    // col within the published half
#pragma unroll
        for (int rg = 0; rg < 16; rg++) {
            const int row = (rg & 3) + ((rg >> 2) << 3) + (half << 2);
            float hOld = bf2f(Ohi[row][j]) + bf2f(Olo[row][j]);
            float rr = 1.f / (1.f + __expf(-aRs[rg]));
            float zz = 1.f / (1.f + __expf(-aZs[rg]));
            float nx = aNis[rg] + rr * aNhs[rg];
            float e  = __expf(-2.f * fabsf(nx));
            float th = 1.f - 2.f * e / (1.f + e);
            th = (nx < 0.f) ? -th : th;
            float hNew = (1.f - zz) * th + zz * hOld;
            unsigned short hi_ = f2bf_rne(hNew);
            unsigned short lo_ = f2bf_rne(hNew - bf2f(hi_));
            Ohi[row][j] = hi_;
            Olo[row][j] = lo_;
            if (xb)
                __hip_atomic_store(&xb[row * 128 + c],
                                   (uint32_t)hi_ | ((uint32_t)lo_ << 16),
                                   __ATOMIC_RELAXED, __HIP_MEMORY_SCOPE_AGENT);
            if (gather && t == lenS[row] - 1)
                friend_last[(size_t)sidS[row] * HD + j] = hNew;
        }
    };

    // pull partner's 32x128 half into the LDS planes (sc0 L1-bypass loads;
    // same-XCD L2 is coherent -> fresh, no invalidates).
    auto pullPartner = [&](uint32_t* xr, int oth,
                           unsigned short (*Ohi)[XP], unsigned short (*Olo)[XP]) {
        for (int i = tid; i < 4096; i += 256) {
            uint32_t v = __hip_atomic_load(&xr[i], __ATOMIC_RELAXED,
                                           __HIP_MEMORY_SCOPE_AGENT);
            int row = i >> 7, c = i & 127;
            int col = oth * 128 + c;
            Ohi[row][col] = (unsigned short)(v & 0xffffu);
            Olo[row][col] = (unsigned short)(v >> 16);
        }
    };

    auto stageWrite = [&](const float4* sx) {
#pragma unroll
        for (int r = 0; r < 8; r++) {
            int row = wv * 8 + r;
            float vals[4] = { sx[r].x, sx[r].y, sx[r].z, sx[r].w };
            u16x4 hi4, lo4;
#pragma unroll
            for (int e2 = 0; e2 < 4; e2++) {
                unsigned short h_ = f2bf_rne(vals[e2]);
                hi4[e2] = h_;
                lo4[e2] = f2bf_rne(vals[e2] - bf2f(h_));
            }
            *(u16x4*)&Xhi[row][lane * 4] = hi4;
            *(u16x4*)&Xlo[row][lane * 4] = lo4;
        }
    };

    // stage x(0)
    {
        float4 sx[8];
#pragma unroll
        for (int r = 0; r < 8; r++)
            sx[r] = ((const float4*)(friend_x + ((size_t)srow[r] * LL) * HD))[lane];
        stageWrite(sx);
    }
    __syncthreads();

    if (paired) {
        const int cw  = role * 4 + wv;
        const int oth = role ^ 1;
        const int j0  = cw * 32 + l31;
        float b0R  = bih0[j0] + bhh0[j0];
        float b0Z  = bih0[256 + j0] + bhh0[256 + j0];
        float b0Ni = bih0[512 + j0];
        float b0Nh = bhh0[512 + j0];
        float b1R  = bih1[j0] + bhh1[j0];
        float b1Z  = bih1[256 + j0] + bhh1[256 + j0];
        float b1Ni = bih1[512 + j0];
        float b1Nh = bhh1[512 + j0];
        const unsigned short* pw0 = wpk + (size_t)(cw * 2 + 0) * 98304 + (size_t)lane * 8;
        const unsigned short* pw1 = wpk + (size_t)(cw * 2 + 1) * 98304 + (size_t)lane * 8;
        int* fl0o = &ctrl[(g * 2 + 0) * 2 + role];
        int* fl0p = &ctrl[(g * 2 + 0) * 2 + oth];
        int* fl1o = &ctrl[(g * 2 + 1) * 2 + role];
        int* fl1p = &ctrl[(g * 2 + 1) * 2 + oth];

#pragma unroll 1
        for (int t = 0; t < maxlen; t++) {
            int par = t & 1;
            uint32_t* xb0 = xbuf + ((((size_t)par * NPAIR + g) * 2 + 0) * 2 + role) * 4096;
            uint32_t* xb1 = xbuf + ((((size_t)par * NPAIR + g) * 2 + 1) * 2 + role) * 4096;
            uint32_t* xr0 = xbuf + ((((size_t)par * NPAIR + g) * 2 + 0) * 2 + oth) * 4096;
            uint32_t* xr1 = xbuf + ((((size_t)par * NPAIR + g) * 2 + 1) * 2 + oth) * 4096;

            int tn = (t + 1 < maxlen) ? t + 1 : t;
            float4 sx[8];
#pragma unroll
            for (int r = 0; r < 8; r++)
                sx[r] = ((const float4*)(friend_x + ((size_t)srow[r] * LL + tn) * HD))[lane];

            // ---- Layer 0 ----
            f32x16 aR, aZ, aNi, aNh;
            initAcc(aR, b0R); initAcc(aZ, b0Z); initAcc(aNi, b0Ni); initAcc(aNh, b0Nh);
            halfMM(pw0,         &Xhi[0][0],  &Xlo[0][0],  aR, aZ, aNi);
            halfMM(pw0 + 49152, &H0hi[0][0], &H0lo[0][0], aR, aZ, aNh);
            __syncthreads();                   // plane reads complete
            epi(aR, aZ, aNi, aNh, H0hi, H0lo, xb0, j0, false, t);
            stageWrite(sx);
            __syncthreads();                   // vmcnt(0) drain: xb0 at L2
            if (tid == 0) {
                __hip_atomic_exchange(fl0o, t + 1, __ATOMIC_RELAXED, __HIP_MEMORY_SCOPE_AGENT);
                while (__hip_atomic_fetch_add(fl0p, 0, __ATOMIC_RELAXED,
                                              __HIP_MEMORY_SCOPE_AGENT) < t + 1)
                    __builtin_amdgcn_s_sleep(2);
            }
            __syncthreads();
            pullPartner(xr0, oth, H0hi, H0lo);
            __syncthreads();                   // H0 complete (both halves)

            // ---- Layer 1 ----
            initAcc(aR, b1R); initAcc(aZ, b1Z); initAcc(aNi, b1Ni); initAcc(aNh, b1Nh);
            halfMM(pw1,         &H0hi[0][0], &H0lo[0][0], aR, aZ, aNi);
            halfMM(pw1 + 49152, &H1hi[0][0], &H1lo[0][0], aR, aZ, aNh);
            __syncthreads();
            epi(aR, aZ, aNi, aNh, H1hi, H1lo, xb1, j0, true, t);
            __syncthreads();                   // vmcnt(0) drain: xb1 at L2
            if (tid == 0) {
                __hip_atomic_exchange(fl1o, t + 1, __ATOMIC_RELAXED, __HIP_MEMORY_SCOPE_AGENT);
                while (__hip_atomic_fetch_add(fl1p, 0, __ATOMIC_RELAXED,
                                              __HIP_MEMORY_SCOPE_AGENT) < t + 1)
                    __builtin_amdgcn_s_sleep(2);
            }
            __syncthreads();
            pullPartner(xr1, oth, H1hi, H1lo);
            __syncthreads();                   // H1 complete for t+1
        }
    } else {
        // ---- SOLO fallback: compute BOTH column halves, no exchange ----
        const int cwA = wv, cwB = 4 + wv;
        const int jA = cwA * 32 + l31, jB = cwB * 32 + l31;
        float b0RA  = bih0[jA] + bhh0[jA],            b0RB  = bih0[jB] + bhh0[jB];
        float b0ZA  = bih0[256 + jA] + bhh0[256 + jA], b0ZB = bih0[256 + jB] + bhh0[256 + jB];
        float b0NiA = bih0[512 + jA],                  b0NiB = bih0[512 + jB];
        float b0NhA = bhh0[512 + jA],                  b0NhB = bhh0[512 + jB];
        float b1RA  = bih1[jA] + bhh1[jA],            b1RB  = bih1[jB] + bhh1[jB];
        float b1ZA  = bih1[256 + jA] + bhh1[256 + jA], b1ZB = bih1[256 + jB] + bhh1[256 + jB];
        float b1NiA = bih1[512 + jA],                  b1NiB = bih1[512 + jB];
        float b1NhA = bhh1[512 + jA],                  b1NhB = bhh1[512 + jB];
        const unsigned short* pw0A = wpk + (size_t)(cwA * 2 + 0) * 98304 + (size_t)lane * 8;
        const unsigned short* pw1A = wpk + (size_t)(cwA * 2 + 1) * 98304 + (size_t)lane * 8;
        const unsigned short* pw0B = wpk + (size_t)(cwB * 2 + 0) * 98304 + (size_t)lane * 8;
        const unsigned short* pw1B = wpk + (size_t)(cwB * 2 + 1) * 98304 + (size_t)lane * 8;

#pragma unroll 1
        for (int t = 0; t < maxlen; t++) {
            int tn = (t + 1 < maxlen) ? t + 1 : t;
            float4 sx[8];
#pragma unroll
            for (int r = 0; r < 8; r++)
                sx[r] = ((const float4*)(friend_x + ((size_t)srow[r] * LL + tn) * HD))[lane];

            // ---- Layer 0, both halves ----
            f32x16 aR0, aZ0, aNi0, aNh0, aR1, aZ1, aNi1, aNh1;
            initAcc(aR0, b0RA); initAcc(aZ0, b0ZA); initAcc(aNi0, b0NiA); initAcc(aNh0, b0NhA);
            initAcc(aR1, b0RB); initAcc(aZ1, b0ZB); initAcc(aNi1, b0NiB); initAcc(aNh1, b0NhB);
            halfMM(pw0A,         &Xhi[0][0],  &Xlo[0][0],  aR0, aZ0, aNi0);
            halfMM(pw0A + 49152, &H0hi[0][0], &H0lo[0][0], aR0, aZ0, aNh0);
            halfMM(pw0B,         &Xhi[0][0],  &Xlo[0][0],  aR1, aZ1, aNi1);
            halfMM(pw0B + 49152, &H0hi[0][0], &H0lo[0][0], aR1, aZ1, aNh1);
            __syncthreads();
            epi(aR0, aZ0, aNi0, aNh0, H0hi, H0lo, nullptr, jA, false, t);
            epi(aR1, aZ1, aNi1, aNh1, H0hi, H0lo, nullptr, jB, false, t);
            stageWrite(sx);
            __syncthreads();

            // ---- Layer 1, both halves ----
            initAcc(aR0, b1RA); initAcc(aZ0, b1ZA); initAcc(aNi0, b1NiA); initAcc(aNh0, b1NhA);
            initAcc(aR1, b1RB); initAcc(aZ1, b1ZB); initAcc(aNi1, b1NiB); initAcc(aNh1, b1NhB);
            halfMM(pw1A,         &H0hi[0][0], &H0lo[0][0], aR0, aZ0, aNi0);
            halfMM(pw1A + 49152, &H1hi[0][0], &H1lo[0][0], aR0, aZ0, aNh0);
            halfMM(pw1B,         &H0hi[0][0], &H0lo[0][0], aR1, aZ1, aNi1);
            halfMM(pw1B + 49152, &H1hi[0][0], &H1lo[0][0], aR1, aZ1, aNh1);
            __syncthreads();
            epi(aR0, aZ0, aNi0, aNh0, H1hi, H1lo, nullptr, jA, true, t);
            epi(aR1, aZ1, aNi1, aNh1, H1hi, H1lo, nullptr, jB, true, t);
            __syncthreads();
        }
    }
}

// ---------------------------------------------------------------------------
// Fused: sf[n,h] = Wf[h,:256]·self_x[b] + Wf[h,256:]·fl[n]; v[n,h] = Wb[:,h]·sf[n,:]
// ---------------------------------------------------------------------------
__global__ __launch_bounds__(256)
void sfv_kernel(const float* __restrict__ self_x, const float* __restrict__ fl,
                const float* __restrict__ WfT, const float* __restrict__ Wb,
                float* __restrict__ vout) {
    __shared__ float S[256];
    __shared__ float T[256][33];   // phase1: fl^T [k][f]; phase2: sf^T [g][f]
    int b = blockIdx.x, tid = threadIdx.x;
    S[tid] = self_x[b * 256 + tid];
    for (int i = tid; i < 32 * 256; i += 256) {
        int f = i >> 8, k = i & 255;
        T[k][f] = fl[((size_t)(b * 32 + f)) * 256 + k];
    }
    __syncthreads();
    float acc0 = 0.f;
    for (int k = 0; k < 256; k++) acc0 += WfT[k * 256 + tid] * S[k];
    float acc[32];
#pragma unroll
    for (int f = 0; f < 32; f++) acc[f] = acc0;
    for (int k = 0; k < 256; k++) {
        float w = WfT[(256 + k) * 256 + tid];
#pragma unroll
        for (int f = 0; f < 32; f++) acc[f] += w * T[k][f];
    }
    __syncthreads();
#pragma unroll
    for (int f = 0; f < 32; f++) T[tid][f] = acc[f];   // sf^T into LDS
    __syncthreads();
    float av[32];
#pragma unroll
    for (int f = 0; f < 32; f++) av[f] = 0.f;
    for (int gg = 0; gg < 256; gg++) {
        float w = Wb[gg * 256 + tid];
#pragma unroll
        for (int f = 0; f < 32; f++) av[f] += w * T[gg][f];
    }
#pragma unroll
    for (int f = 0; f < 32; f++)
        vout[((size_t)(b * 32 + f)) * 256 + tid] = av[f];
}

// ---------------------------------------------------------------------------
// tf[n] = sum_s softplus(common_x[n,s,:]·v[n,:]) * exp(-time) * (s < clen)
// ---------------------------------------------------------------------------
__global__ __launch_bounds__(256)
void tf_kernel(const float* __restrict__ common_x, const float* __restrict__ common_time,
               const int* __restrict__ clen, const float* __restrict__ v,
               float* __restrict__ tf) {
    __shared__ float V[256];
    __shared__ float partial[4];
    int n = blockIdx.x, tid = threadIdx.x, wv = tid >> 6, lane = tid & 63;
    V[tid] = v[(size_t)n * 256 + tid];
    __syncthreads();
    float4 vv = ((const float4*)V)[lane];
    int cl = clen[n];
    float acc = 0.f;
    for (int s = wv; s < SS; s += 4) {
        float4 cx = ((const float4*)(common_x + ((size_t)n * SS + s) * HD))[lane];
        float d = cx.x * vv.x + cx.y * vv.y + cx.z * vv.z + cx.w * vv.w;
#pragma unroll
        for (int off = 32; off; off >>= 1) d += __shfl_xor(d, off);
        if (lane == 0 && s < cl) {
            float sp = (d > 20.f) ? d : log1pf(__expf(d));
            acc += sp * __expf(-common_time[n * SS + s]);
        }
    }
    if (lane == 0) partial[wv] = acc;
    __syncthreads();
    if (tid == 0) tf[n] = partial[0] + partial[1] + partial[2] + partial[3];
}

// ---------------------------------------------------------------------------
// softmax over padded MAXF (invalid logits exactly 0) + weighted sum.
// ---------------------------------------------------------------------------
__global__ __launch_bounds__(256)
void out_kernel(const float* __restrict__ tf, const int* __restrict__ fnum,
                const float* __restrict__ fl, float* __restrict__ out) {
    __shared__ float e[32];
    __shared__ float tfm[32];
    __shared__ float Zs;
    int b = blockIdx.x, tid = threadIdx.x;
    int nv = fnum[b];
    if (tid < 32) tfm[tid] = (tid < nv) ? tf[b * 32 + tid] : 0.f;
    __syncthreads();
    if (tid == 0) {
        float m = tfm[0];
        for (int f = 1; f < 32; f++) m = fmaxf(m, tfm[f]);
        float Z = 0.f;
        for (int f = 0; f < 32; f++) { e[f] = __expf(tfm[f] - m); Z += e[f]; }
        Zs = Z;
    }
    __syncthreads();
    float Zi = 1.f / Zs;
    float o = 0.f;
    for (int f = 0; f < nv; f++)
        o += e[f] * Zi * fl[((size_t)(b * 32 + f)) * 256 + tid];
    out[b * 256 + tid] = o;
}

// ---------------------------------------------------------------------------
extern "C" void kernel_launch(void* const* d_in, const int* in_sizes, int n_in,
                              void* d_out, int out_size, void* d_ws, size_t ws_size,
                              hipStream_t stream) {
    (void)in_sizes; (void)n_in; (void)out_size; (void)ws_size;
    const float* self_x      = (const float*)d_in[0];
    const float* common_x    = (const float*)d_in[1];
    const float* common_time = (const float*)d_in[2];
    const float* friend_x    = (const float*)d_in[3];
    const float* Wih0 = (const float*)d_in[4];
    const float* Whh0 = (const float*)d_in[5];
    const float* bih0 = (const float*)d_in[6];
    const float* bhh0 = (const float*)d_in[7];
    const float* Wih1 = (const float*)d_in[8];
    const float* Whh1 = (const float*)d_in[9];
    const float* bih1 = (const float*)d_in[10];
    const float* bhh1 = (const float*)d_in[11];
    const float* Wf   = (const float*)d_in[12];
    const float* Wb   = (const float*)d_in[13];
    const int* flen   = (const int*)d_in[14];
    const int* fnum   = (const int*)d_in[15];
    const int* clen   = (const int*)d_in[16];
    float* out = (float*)d_out;

    char* ws = (char*)d_ws;
    unsigned short* wpk = (unsigned short*)ws; ws += (size_t)1572864 * 2;
    float* WfT = (float*)ws;  ws += (size_t)512 * 256 * 4;
    int*   sid = (int*)ws;    ws += (size_t)2048 * 4;
    float* fl  = (float*)ws;  ws += (size_t)2048 * 256 * 4;
    float* vv  = (float*)ws;  ws += (size_t)2048 * 256 * 4;
    float* tf  = (float*)ws;  ws += (size_t)2048 * 4;
    uint32_t* xbuf = (uint32_t*)ws; ws += (size_t)2 * NPAIR * 2 * 2 * 4096 * 4; // 8 MB
    int* ctrl = (int*)ws;     ws += (size_t)512 * 4;

    pack_kernel<<<6656, 256, 0, stream>>>(Wih0, Whh0, Wih1, Whh1, Wf, wpk, WfT);
    sort_kernel<<<1, 256, 0, stream>>>(flen, sid, ctrl);
    gru_kernel<<<128, 256, 0, stream>>>(friend_x, flen, sid, wpk,
                                        bih0, bhh0, bih1, bhh1, fl, xbuf, ctrl);
    sfv_kernel<<<64, 256, 0, stream>>>(self_x, fl, WfT, Wb, vv);
    tf_kernel<<<2048, 256, 0, stream>>>(common_x, common_time, clen, vv, tf);
    out_kernel<<<64, 256, 0, stream>>>(tf, fnum, fl, out);
}

// Round 7
// 2435.012 us; speedup vs baseline: 2.2752x; 1.9457x over previous
//
#include <hip/hip_runtime.h>
#include <hip/hip_bf16.h>
#include <stdint.h>

// Problem constants
#define HD    256      // hidden
#define LL    50       // friend seq len
#define SS    50       // common seq len
#define NB    64       // batch
#define MAXF  32
#define NSEQ  2048     // NB*MAXF
#define MB    32       // sequences per block (one 32-row MFMA M-tile)
#define NBLK  64       // NSEQ/MB
#define XP    264      // padded LDS row (bf16 elems): 528B rows, 16B aligned

typedef __attribute__((ext_vector_type(8)))  short bf16x8;
typedef __attribute__((ext_vector_type(16))) float f32x16;
typedef __attribute__((ext_vector_type(4)))  unsigned short u16x4;

__device__ __forceinline__ f32x16 mfma32(bf16x8 a, bf16x8 b, f32x16 c) {
    return __builtin_amdgcn_mfma_f32_32x32x16_bf16(a, b, c, 0, 0, 0);
}

__device__ __forceinline__ unsigned short f2bf_rne(float f) {
    union { float f; uint32_t u; } v; v.f = f;
    uint32_t u = v.u;
    uint32_t r = u + 0x7FFFu + ((u >> 16) & 1u);
    return (unsigned short)(r >> 16);
}
__device__ __forceinline__ float bf2f(unsigned short b) {
    union { float f; uint32_t u; } v; v.u = ((uint32_t)b) << 16;
    return v.f;
}

// ---------------------------------------------------------------------------
// Pack weights -> per-wave MFMA 32x32x16 fragment stream + Wf^T.
// 8-wave layout: wpk index = ((((wv*2+l)*2 + m)*16 + ks)*6 + fr)*512 + lane*8 + j
//   fr = gate*2 + plane  (gate r/z/n, plane hi/lo)
//   W row n = gate*256 + wv*32 + (lane&31)     (wave wv owns cols [32wv,32wv+32))
//   k       = ks*16 + (lane>>5)*8 + j
// ---------------------------------------------------------------------------
__global__ void pack_kernel(const float* __restrict__ Wih0, const float* __restrict__ Whh0,
                            const float* __restrict__ Wih1, const float* __restrict__ Whh1,
                            const float* __restrict__ Wf,
                            unsigned short* __restrict__ wpk,
                            float* __restrict__ WfT) {
    int idx = blockIdx.x * blockDim.x + threadIdx.x;
    const int TOTW = 1572864;
    if (idx < TOTW) {
        int j    = idx & 7;
        int lane = (idx >> 3) & 63;
        int fr   = (idx >> 9) % 6;
        int t2   = (idx >> 9) / 6;           // ((wv*2+l)*2+m)*16+ks
        int ks   = t2 & 15;
        int m    = (t2 >> 4) & 1;
        int l    = (t2 >> 5) & 1;
        int wvv  = t2 >> 6;                  // 0..7
        int gate = fr >> 1, plane = fr & 1;
        const float* W = (l == 0) ? (m == 0 ? Wih0 : Whh0)
                                  : (m == 0 ? Wih1 : Whh1);
        int n = gate * 256 + wvv * 32 + (lane & 31);
        int k = ks * 16 + (lane >> 5) * 8 + j;
        float v = W[n * HD + k];
        unsigned short hi = f2bf_rne(v);
        wpk[idx] = plane ? f2bf_rne(v - bf2f(hi)) : hi;
    } else {
        int idx2 = idx - TOTW;
        if (idx2 < 512 * 256) {              // WfT[k][h] = Wf[h][k]
            int k = idx2 >> 8; int h = idx2 & 255;
            WfT[k * 256 + h] = Wf[h * 512 + k];
        }
    }
}

// ---------------------------------------------------------------------------
// Counting sort of the 2048 sequences by friend_len (1..50), ascending.
// ---------------------------------------------------------------------------
__global__ void sort_kernel(const int* __restrict__ flen, int* __restrict__ sid) {
    __shared__ int hist[64];
    __shared__ int offs[64];
    int tid = threadIdx.x;
    if (tid < 64) hist[tid] = 0;
    __syncthreads();
    for (int i = tid; i < NSEQ; i += blockDim.x) atomicAdd(&hist[flen[i]], 1);
    __syncthreads();
    if (tid == 0) {
        int acc = 0;
        for (int v = 1; v <= 50; v++) { offs[v] = acc; acc += hist[v]; }
    }
    __syncthreads();
    for (int i = tid; i < NSEQ; i += blockDim.x) {
        int pos = atomicAdd(&offs[flen[i]], 1);
        sid[pos] = i;
    }
}

// ---------------------------------------------------------------------------
// Precompute layer-0 INPUT gates: G[g][t][row][j] = bias_j + x(seq,t)·Wih0^T_j
// (j in [0,768): r | z | n-input). Uses the IDENTICAL fragment values, acc
// init, and per-acc MFMA chain order (ah·Bhi, al·Bhi, ah·Blo; ks ascending)
// as the recurrent kernel's X-half did in round 3 -> G is bit-identical to
// the post-X-halfMM accumulators, so the final output is bit-identical.
// x(t) is NOT recurrent, so this is embarrassingly parallel: 128 blocks
// (2 per group, interleaved 4-timestep chunks), 4 waves; each wave owns 6 of
// the 24 (gate, 32-col) subtiles; per subtile all 16 ks weight frags (32 x
// 1KB loads, ~32KB in flight) are loaded up-front to amortize LLC latency.
// ---------------------------------------------------------------------------
__global__ __launch_bounds__(256) __attribute__((amdgpu_waves_per_eu(1, 1)))
void mmih_kernel(const float* __restrict__ friend_x,
                 const int* __restrict__ flen,
                 const int* __restrict__ sid,
                 const unsigned short* __restrict__ wpk,
                 const float* __restrict__ bih0, const float* __restrict__ bhh0,
                 float* __restrict__ Gp) {
    __shared__ __align__(16) unsigned short XHi[4][MB][XP], XLo[4][MB][XP];
    __shared__ int sidS[MB], lenS[MB];
    const int tid  = threadIdx.x;
    const int g    = blockIdx.x >> 1;
    const int par  = blockIdx.x & 1;
    const int wv   = tid >> 6;
    const int lane = tid & 63;
    const int l31  = lane & 31;
    const int half = lane >> 5;

    if (tid < MB) {
        int s_ = sid[g * MB + tid];
        sidS[tid] = s_;
        lenS[tid] = flen[s_];
    }
    __syncthreads();
    int maxlen = 0;
#pragma unroll
    for (int s = 0; s < MB; s++) maxlen = max(maxlen, lenS[s]);

    const int fragBaseT = l31 * XP + half * 8;
    float* Gbase = Gp + (size_t)g * 50 * 32 * 768;

    for (int t0 = par * 4; t0 < maxlen; t0 += 8) {
        int nt = maxlen - t0; if (nt > 4) nt = 4;
        // stage: wave wv stages timestep t0+wv (hi/lo split, same as gru R3)
        if (wv < nt) {
            int tt = t0 + wv;
            for (int r = 0; r < MB; r++) {
                float4 v = ((const float4*)(friend_x + ((size_t)sidS[r] * LL + tt) * HD))[lane];
                float vals[4] = { v.x, v.y, v.z, v.w };
                u16x4 hi4, lo4;
#pragma unroll
                for (int e2 = 0; e2 < 4; e2++) {
                    unsigned short h_ = f2bf_rne(vals[e2]);
                    hi4[e2] = h_;
                    lo4[e2] = f2bf_rne(vals[e2] - bf2f(h_));
                }
                *(u16x4*)&XHi[wv][r][lane * 4] = hi4;
                *(u16x4*)&XLo[wv][r][lane * 4] = lo4;
            }
        }
        __syncthreads();
        // compute: 6 (gate, col32) subtiles per wave
        for (int s6 = 0; s6 < 6; s6++) {
            int s    = wv * 6 + s6;          // 0..23
            int gate = s >> 3, w8 = s & 7;
            int j    = gate * 256 + w8 * 32 + l31;
            float bias = (gate < 2) ? (bih0[j] + bhh0[j]) : bih0[j];
            // all 16 ks frag pairs up-front (128 VGPR; 1 wave/SIMD budget)
            bf16x8 BH[16], BL[16];
            const unsigned short* pb = wpk + ((size_t)(64 * w8) * 6 + gate * 2) * 512
                                           + (size_t)lane * 8;
#pragma unroll
            for (int ks = 0; ks < 16; ks++) {
                BH[ks] = *(const bf16x8*)(pb + (size_t)ks * 3072);
                BL[ks] = *(const bf16x8*)(pb + (size_t)ks * 3072 + 512);
            }
            f32x16 acc0, acc1, acc2, acc3;
            {
                f32x16 v;
#pragma unroll
                for (int i = 0; i < 16; i++) v[i] = bias;
                acc0 = v; acc1 = v; acc2 = v; acc3 = v;
            }
#pragma unroll
            for (int ks = 0; ks < 16; ks++) {
                // per-acc chain order matches R3 compute9: ah·Bhi, al·Bhi, ah·Blo
#define MM_T(TT, ACC)                                                              \
                if (TT < nt) {                                                     \
                    bf16x8 ah = *(const bf16x8*)(&XHi[TT][0][0] + fragBaseT + ks * 16); \
                    bf16x8 al = *(const bf16x8*)(&XLo[TT][0][0] + fragBaseT + ks * 16); \
                    ACC = mfma32(ah, BH[ks], ACC);                                 \
                    ACC = mfma32(al, BH[ks], ACC);                                 \
                    ACC = mfma32(ah, BL[ks], ACC);                                 \
                }
                MM_T(0, acc0) MM_T(1, acc1) MM_T(2, acc2) MM_T(3, acc3)
#undef MM_T
            }
            // store: C-layout col = lane&31, row = (rg&3)+8*(rg>>2)+4*half
#define ST_T(TT, ACC)                                                              \
            if (TT < nt) {                                                         \
                float* Gt = Gbase + (size_t)(t0 + TT) * 32 * 768;                  \
                _Pragma("unroll")                                                  \
                for (int rg = 0; rg < 16; rg++) {                                  \
                    int row = (rg & 3) + ((rg >> 2) << 3) + (half << 2);           \
                    Gt[row * 768 + j] = ACC[rg];                                   \
                }                                                                  \
            }
            ST_T(0, acc0) ST_T(1, acc1) ST_T(2, acc2) ST_T(3, acc3)
#undef ST_T
        }
        __syncthreads();
    }
}

// ---------------------------------------------------------------------------
// Fused 2-layer GRU (round-3 structure: 512 thr = 8 waves, 2 waves/SIMD,
// 2-buffer weight ping-pong, no spills). useG=1: layer-0 input gates are
// PRELOADED from Gp (precomputed x·Wih0) -> weight stream per step drops
// 3 MB -> 2.25 MB (+98 KB G), bit-identical math. useG=0: exact round-3
// fallback (X staged in LDS, both layer-0 halfMMs) for small workspaces.
// ---------------------------------------------------------------------------
__global__ __launch_bounds__(512, 2) __attribute__((amdgpu_waves_per_eu(2, 2)))
void gru_kernel(const float* __restrict__ friend_x,
                const int* __restrict__ flen,
                const int* __restrict__ sid,
                const unsigned short* __restrict__ wpk,
                const float* __restrict__ bih0, const float* __restrict__ bhh0,
                const float* __restrict__ bih1, const float* __restrict__ bhh1,
                float* __restrict__ friend_last,
                const float* __restrict__ Gp, int useG) {
    __shared__ __align__(16) unsigned short Xhi[MB][XP],  Xlo[MB][XP];
    __shared__ __align__(16) unsigned short H0hi[MB][XP], H0lo[MB][XP];
    __shared__ __align__(16) unsigned short H1hi[MB][XP], H1lo[MB][XP];
    __shared__ int sidS[MB], lenS[MB];

    const int tid  = threadIdx.x;
    const int g    = blockIdx.x;
    const int wv   = tid >> 6;          // 0..7
    const int lane = tid & 63;
    const int l31  = lane & 31;
    const int half = lane >> 5;

    if (tid < MB) {
        int s_ = sid[g * MB + tid];
        sidS[tid] = s_;
        lenS[tid] = flen[s_];
    }
    for (int i = tid; i < MB * XP / 2; i += 512) {
        ((uint32_t*)&H0hi[0][0])[i] = 0; ((uint32_t*)&H0lo[0][0])[i] = 0;
        ((uint32_t*)&H1hi[0][0])[i] = 0; ((uint32_t*)&H1lo[0][0])[i] = 0;
    }
    __syncthreads();

    int maxlen = 0;
#pragma unroll
    for (int s = 0; s < MB; s++) maxlen = max(maxlen, lenS[s]);

    const int j0 = wv * 32 + l31;       // this lane's gate column

    float b0R  = bih0[j0] + bhh0[j0];
    float b0Z  = bih0[256 + j0] + bhh0[256 + j0];
    float b0Ni = bih0[512 + j0];
    float b0Nh = bhh0[512 + j0];
    float b1R  = bih1[j0] + bhh1[j0];
    float b1Z  = bih1[256 + j0] + bhh1[256 + j0];
    float b1Ni = bih1[512 + j0];
    float b1Nh = bhh1[512 + j0];

    int srow[4];                        // staged sequence ids (rows wv*4..wv*4+3)
#pragma unroll
    for (int r = 0; r < 4; r++) srow[r] = sidS[wv * 4 + r];

    const int fragBase = l31 * XP + half * 8;

    auto loadB6 = [&](bf16x8* B, const unsigned short* p) {
#pragma unroll
        for (int f = 0; f < 6; f++) B[f] = *(const bf16x8*)(p + f * 512);
    };

    auto compute9 = [&](const bf16x8* B, bf16x8 ah, bf16x8 al,
                        f32x16& aRs, f32x16& aZs, f32x16& aNs) {
        aRs = mfma32(ah, B[0], aRs);
        aZs = mfma32(ah, B[2], aZs);
        aNs = mfma32(ah, B[4], aNs);
        aRs = mfma32(al, B[0], aRs);
        aZs = mfma32(al, B[2], aZs);
        aNs = mfma32(al, B[4], aNs);
        aRs = mfma32(ah, B[1], aRs);
        aZs = mfma32(ah, B[3], aZs);
        aNs = mfma32(ah, B[5], aNs);
    };

    // one m-phase (16 K-steps): 2-buffer ping-pong (48 arch VGPRs, no spill)
    auto halfMM = [&](const unsigned short* pm,
                      const unsigned short* Ah_, const unsigned short* Al_,
                      f32x16& aRs, f32x16& aZs, f32x16& aNs) {
        bf16x8 B0[6], B1[6];
        loadB6(B0, pm);
        loadB6(B1, pm + 3072);
        bf16x8 ahA = *(const bf16x8*)(Ah_ + fragBase);
        bf16x8 alA = *(const bf16x8*)(Al_ + fragBase);
        bf16x8 ahB, alB;
#pragma unroll 1
        for (int ks = 0; ks < 16; ks += 2) {
            ahB = *(const bf16x8*)(Ah_ + fragBase + (ks + 1) * 16);
            alB = *(const bf16x8*)(Al_ + fragBase + (ks + 1) * 16);
            compute9(B0, ahA, alA, aRs, aZs, aNs);
            if (ks + 2 < 16) {
                loadB6(B0, pm + (size_t)(ks + 2) * 3072);
                ahA = *(const bf16x8*)(Ah_ + fragBase + (ks + 2) * 16);
                alA = *(const bf16x8*)(Al_ + fragBase + (ks + 2) * 16);
            }
            compute9(B1, ahB, alB, aRs, aZs, aNs);
            if (ks + 3 < 16) loadB6(B1, pm + (size_t)(ks + 3) * 3072);
        }
    };

    auto initAcc = [&](f32x16& a, float b) {
        f32x16 v;
#pragma unroll
        for (int i = 0; i < 16; i++) v[i] = b;
        a = v;
    };

    auto epi = [&](f32x16& aRs, f32x16& aZs, f32x16& aNis, f32x16& aNhs,
                   unsigned short (*Ohi)[XP], unsigned short (*Olo)[XP],
                   bool gather, int t) {
        const int j = j0;
#pragma unroll
        for (int rg = 0; rg < 16; rg++) {
            const int row = (rg & 3) + ((rg >> 2) << 3) + (half << 2);
            float hOld = bf2f(Ohi[row][j]) + bf2f(Olo[row][j]);
            float rr = 1.f / (1.f + __expf(-aRs[rg]));
            float zz = 1.f / (1.f + __expf(-aZs[rg]));
            float nx = aNis[rg] + rr * aNhs[rg];
            float e  = __expf(-2.f * fabsf(nx));
            float th = 1.f - 2.f * e / (1.f + e);
            th = (nx < 0.f) ? -th : th;
            float hNew = (1.f - zz) * th + zz * hOld;
            unsigned short hi_ = f2bf_rne(hNew);
            Ohi[row][j] = hi_;
            Olo[row][j] = f2bf_rne(hNew - bf2f(hi_));
            if (gather && t == lenS[row] - 1)
                friend_last[(size_t)sidS[row] * HD + j] = hNew;
        }
    };

    auto stageWrite = [&](const float4* sx) {
#pragma unroll
        for (int r = 0; r < 4; r++) {
            int row = wv * 4 + r;
            float vals[4] = { sx[r].x, sx[r].y, sx[r].z, sx[r].w };
            u16x4 hi4, lo4;
#pragma unroll
            for (int e2 = 0; e2 < 4; e2++) {
                unsigned short h_ = f2bf_rne(vals[e2]);
                hi4[e2] = h_;
                lo4[e2] = f2bf_rne(vals[e2] - bf2f(h_));
            }
            *(u16x4*)&Xhi[row][lane * 4] = hi4;
            *(u16x4*)&Xlo[row][lane * 4] = lo4;
        }
    };

    if (!useG) {   // stage x(0) for fallback path
        float4 sx[4];
#pragma unroll
        for (int r = 0; r < 4; r++)
            sx[r] = ((const float4*)(friend_x + ((size_t)srow[r] * LL) * HD))[lane];
        stageWrite(sx);
    }
    __syncthreads();

    // per-wave weight bases: (wv*2+l)*98304 ; +49152 for the m-phase
    const unsigned short* pw0 = wpk + (size_t)(wv * 2 + 0) * 98304 + (size_t)lane * 8;
    const unsigned short* pw1 = wpk + (size_t)(wv * 2 + 1) * 98304 + (size_t)lane * 8;
    const float* Gbase = Gp + (size_t)g * 50 * 32 * 768;

#pragma unroll 1
    for (int t = 0; t < maxlen; t++) {
        f32x16 aR, aZ, aNi, aNh;
        if (useG) {
            // ---- Layer 0 (fast): acc preloaded with bias + x(t)·Wih0 ----
            const float* Gt = Gbase + (size_t)t * 32 * 768;
#pragma unroll
            for (int rg = 0; rg < 16; rg++) {
                const int row = (rg & 3) + ((rg >> 2) << 3) + (half << 2);
                const float* gr = Gt + row * 768 + j0;
                aR[rg]  = gr[0];
                aZ[rg]  = gr[256];
                aNi[rg] = gr[512];
            }
            initAcc(aNh, b0Nh);
            halfMM(pw0 + 49152, &H0hi[0][0], &H0lo[0][0], aR, aZ, aNh);
            __syncthreads();                   // B1: H0 plane reads complete
            epi(aR, aZ, aNi, aNh, H0hi, H0lo, false, t);
            __syncthreads();                   // B2: h0(t) visible
        } else {
            // ---- Layer 0 (fallback = exact round-3 path) ----
            int tn = (t + 1 < maxlen) ? t + 1 : t;
            float4 sx[4];
#pragma unroll
            for (int r = 0; r < 4; r++)
                sx[r] = ((const float4*)(friend_x + ((size_t)srow[r] * LL + tn) * HD))[lane];
            initAcc(aR, b0R); initAcc(aZ, b0Z); initAcc(aNi, b0Ni); initAcc(aNh, b0Nh);
            halfMM(pw0,         &Xhi[0][0],  &Xlo[0][0],  aR, aZ, aNi);
            halfMM(pw0 + 49152, &H0hi[0][0], &H0lo[0][0], aR, aZ, aNh);
            __syncthreads();                   // B1: X/H0 reads complete
            epi(aR, aZ, aNi, aNh, H0hi, H0lo, false, t);
            stageWrite(sx);                    // write x(t+1)
            __syncthreads();                   // B2: h0(t) + x(t+1) visible
        }
        // ---- Layer 1: gates = h0(t)·Wih1 + h1·Whh1 ----
        initAcc(aR, b1R); initAcc(aZ, b1Z); initAcc(aNi, b1Ni); initAcc(aNh, b1Nh);
        halfMM(pw1,         &H0hi[0][0], &H0lo[0][0], aR, aZ, aNi);
        halfMM(pw1 + 49152, &H1hi[0][0], &H1lo[0][0], aR, aZ, aNh);
        __syncthreads();                       // B3: H0/H1 reads complete
        epi(aR, aZ, aNi, aNh, H1hi, H1lo, true, t);
    }
}

// ---------------------------------------------------------------------------
// Fused: sf[n,h] = Wf[h,:256]·self_x[b] + Wf[h,256:]·fl[n]; v[n,h] = Wb[:,h]·sf[n,:]
// ---------------------------------------------------------------------------
__global__ __launch_bounds__(256)
void sfv_kernel(const float* __restrict__ self_x, const float* __restrict__ fl,
                const float* __restrict__ WfT, const float* __restrict__ Wb,
                float* __restrict__ vout) {
    __shared__ float S[256];
    __shared__ float T[256][33];   // phase1: fl^T [k][f]; phase2: sf^T [g][f]
    int b = blockIdx.x, tid = threadIdx.x;
    S[tid] = self_x[b * 256 + tid];
    for (int i = tid; i < 32 * 256; i += 256) {
        int f = i >> 8, k = i & 255;
        T[k][f] = fl[((size_t)(b * 32 + f)) * 256 + k];
    }
    __syncthreads();
    float acc0 = 0.f;
    for (int k = 0; k < 256; k++) acc0 += WfT[k * 256 + tid] * S[k];
    float acc[32];
#pragma unroll
    for (int f = 0; f < 32; f++) acc[f] = acc0;
    for (int k = 0; k < 256; k++) {
        float w = WfT[(256 + k) * 256 + tid];
#pragma unroll
        for (int f = 0; f < 32; f++) acc[f] += w * T[k][f];
    }
    __syncthreads();
#pragma unroll
    for (int f = 0; f < 32; f++) T[tid][f] = acc[f];   // sf^T into LDS
    __syncthreads();
    float av[32];
#pragma unroll
    for (int f = 0; f < 32; f++) av[f] = 0.f;
    for (int gg = 0; gg < 256; gg++) {
        float w = Wb[gg * 256 + tid];
#pragma unroll
        for (int f = 0; f < 32; f++) av[f] += w * T[gg][f];
    }
#pragma unroll
    for (int f = 0; f < 32; f++)
        vout[((size_t)(b * 32 + f)) * 256 + tid] = av[f];
}

// ---------------------------------------------------------------------------
// tf[n] = sum_s softplus(common_x[n,s,:]·v[n,:]) * exp(-time) * (s < clen)
// ---------------------------------------------------------------------------
__global__ __launch_bounds__(256)
void tf_kernel(const float* __restrict__ common_x, const float* __restrict__ common_time,
               const int* __restrict__ clen, const float* __restrict__ v,
               float* __restrict__ tf) {
    __shared__ float V[256];
    __shared__ float partial[4];
    int n = blockIdx.x, tid = threadIdx.x, wv = tid >> 6, lane = tid & 63;
    V[tid] = v[(size_t)n * 256 + tid];
    __syncthreads();
    float4 vv = ((const float4*)V)[lane];
    int cl = clen[n];
    float acc = 0.f;
    for (int s = wv; s < SS; s += 4) {
        float4 cx = ((const float4*)(common_x + ((size_t)n * SS + s) * HD))[lane];
        float d = cx.x * vv.x + cx.y * vv.y + cx.z * vv.z + cx.w * vv.w;
#pragma unroll
        for (int off = 32; off; off >>= 1) d += __shfl_xor(d, off);
        if (lane == 0 && s < cl) {
            float sp = (d > 20.f) ? d : log1pf(__expf(d));
            acc += sp * __expf(-common_time[n * SS + s]);
        }
    }
    if (lane == 0) partial[wv] = acc;
    __syncthreads();
    if (tid == 0) tf[n] = partial[0] + partial[1] + partial[2] + partial[3];
}

// ---------------------------------------------------------------------------
// softmax over padded MAXF (invalid logits exactly 0) + weighted sum.
// ---------------------------------------------------------------------------
__global__ __launch_bounds__(256)
void out_kernel(const float* __restrict__ tf, const int* __restrict__ fnum,
                const float* __restrict__ fl, float* __restrict__ out) {
    __shared__ float e[32];
    __shared__ float tfm[32];
    __shared__ float Zs;
    int b = blockIdx.x, tid = threadIdx.x;
    int nv = fnum[b];
    if (tid < 32) tfm[tid] = (tid < nv) ? tf[b * 32 + tid] : 0.f;
    __syncthreads();
    if (tid == 0) {
        float m = tfm[0];
        for (int f = 1; f < 32; f++) m = fmaxf(m, tfm[f]);
        float Z = 0.f;
        for (int f = 0; f < 32; f++) { e[f] = __expf(tfm[f] - m); Z += e[f]; }
        Zs = Z;
    }
    __syncthreads();
    float Zi = 1.f / Zs;
    float o = 0.f;
    for (int f = 0; f < nv; f++)
        o += e[f] * Zi * fl[((size_t)(b * 32 + f)) * 256 + tid];
    out[b * 256 + tid] = o;
}

// ---------------------------------------------------------------------------
extern "C" void kernel_launch(void* const* d_in, const int* in_sizes, int n_in,
                              void* d_out, int out_size, void* d_ws, size_t ws_size,
                              hipStream_t stream) {
    (void)in_sizes; (void)n_in; (void)out_size;
    const float* self_x      = (const float*)d_in[0];
    const float* common_x    = (const float*)d_in[1];
    const float* common_time = (const float*)d_in[2];
    const float* friend_x    = (const float*)d_in[3];
    const float* Wih0 = (const float*)d_in[4];
    const float* Whh0 = (const float*)d_in[5];
    const float* bih0 = (const float*)d_in[6];
    const float* bhh0 = (const float*)d_in[7];
    const float* Wih1 = (const float*)d_in[8];
    const float* Whh1 = (const float*)d_in[9];
    const float* bih1 = (const float*)d_in[10];
    const float* bhh1 = (const float*)d_in[11];
    const float* Wf   = (const float*)d_in[12];
    const float* Wb   = (const float*)d_in[13];
    const int* flen   = (const int*)d_in[14];
    const int* fnum   = (const int*)d_in[15];
    const int* clen   = (const int*)d_in[16];
    float* out = (float*)d_out;

    char* ws = (char*)d_ws;
    unsigned short* wpk = (unsigned short*)ws; ws += (size_t)1572864 * 2;
    float* WfT = (float*)ws;  ws += (size_t)512 * 256 * 4;
    int*   sid = (int*)ws;    ws += (size_t)2048 * 4;
    float* fl  = (float*)ws;  ws += (size_t)2048 * 256 * 4;
    float* vv  = (float*)ws;  ws += (size_t)2048 * 256 * 4;
    float* tf  = (float*)ws;  ws += (size_t)2048 * 4;
    // G: 64 groups x 50 t x 32 rows x 768 cols x f32 = 300 MB
    const size_t gNeed = (size_t)64 * 50 * 32 * 768 * 4;
    size_t used = (size_t)(ws - (char*)d_ws);
    int useG = (ws_size >= used + gNeed) ? 1 : 0;
    float* Gp = (float*)ws;

    pack_kernel<<<6656, 256, 0, stream>>>(Wih0, Whh0, Wih1, Whh1, Wf, wpk, WfT);
    sort_kernel<<<1, 256, 0, stream>>>(flen, sid);
    if (useG)
        mmih_kernel<<<128, 256, 0, stream>>>(friend_x, flen, sid, wpk,
                                             bih0, bhh0, Gp);
    gru_kernel<<<NBLK, 512, 0, stream>>>(friend_x, flen, sid, wpk,
                                         bih0, bhh0, bih1, bhh1, fl, Gp, useG);
    sfv_kernel<<<64, 256, 0, stream>>>(self_x, fl, WfT, Wb, vv);
    tf_kernel<<<2048, 256, 0, stream>>>(common_x, common_time, clen, vv, tf);
    out_kernel<<<64, 256, 0, stream>>>(tf, fnum, fl, out);
}